// Round 7
// baseline (71251.331 us; speedup 1.0000x reference)
//
#include <hip/hip_runtime.h>
#include <stdint.h>

typedef unsigned int u32;
typedef float  f32x4 __attribute__((ext_vector_type(4)));

constexpr int NT = 256;   // threads per block
constexpr int BB = 256;   // batch
constexpr int ZD = 256;
constexpr int TD = 512;
constexpr int CF = 1024;
constexpr int G4 = 4096;
constexpr int NA = 64;
constexpr int NSTEP = 64;
constexpr int TS_OFF = BB * NSTEP * NA;   // acts [256][64][64] then ts [256][64]

struct P {
  const float *z, *W_z2t, *b_z2t, *E, *Wih_a, *Whh_a, *bih_a, *bhh_a,
              *Wih_t, *Whh_t, *bih_t, *bhh_t, *W_act, *b_act, *W_ts1, *b_ts1, *W_ts2, *b_ts2;
  float* out;                                               // FLOAT32 output (ref dtype)
  // f64 argmax-critical path
  double *t_rec64, *pre_a64, *E_proj_a64, *h_a64, *c_a64;   // h_a64 double-buffered [2][256][1024]
  // f32 ts path
  float *t_rec32, *pre_t, *E_proj_t, *colt, *h_t, *c_t, *gacc_t, *ts_accum;  // h_t dbuf [2][..]
  int* idxb;
};

__device__ __forceinline__ float sigf(float x){ return 1.f / (1.f + expf(-x)); }
__device__ __forceinline__ float tanhf_(float x){
  float ax = fabsf(x); float e = expf(-2.f * ax);
  float t = 1.f - 2.f * e / (1.f + e);
  return x < 0.f ? -t : t;
}
__device__ __forceinline__ double sigd(double x){ return 1.0 / (1.0 + exp(-x)); }

// ---------------- setup: t_rec (f64+f32), E_proj tables, colt, state init ----------------
__global__ void __launch_bounds__(NT) k_setup(P p){
  __shared__ double sz[ZD];
  const int bid = blockIdx.x, tid = threadIdx.x;
  for (int i = tid; i < ZD; i += NT) sz[i] = (double)p.z[bid * ZD + i];
  __syncthreads();
  for (int k = tid; k < TD; k += NT){
    const float* wr = p.W_z2t + (size_t)k * ZD;
    double a = 0.0;
    for (int j = 0; j < ZD; ++j) a = fma((double)wr[j], sz[j], a);
    a += (double)p.b_z2t[k];
    double t = a > 0.0 ? a : 0.0;
    p.t_rec64[(size_t)bid * TD + k] = t;
    p.t_rec32[(size_t)bid * TD + k] = (float)t;
  }
  for (int i = tid; i < CF; i += NT){
    p.c_a64[(size_t)bid * CF + i] = 0.0;
    p.h_a64[(size_t)bid * CF + i] = 0.0;  // buffer 0
    p.c_t[(size_t)bid * CF + i] = 0.f;
    p.h_t[(size_t)bid * CF + i] = 0.f;    // buffer 0
  }
  if (tid == 0){ p.idxb[bid] = NA - 1; p.ts_accum[bid] = 0.f; }
  __syncthreads();
  if (bid < 64){             // E_proj_a64 row = bid: E[bid] . Wih_a[col, 512:768]
    for (int i = tid; i < ZD; i += NT) sz[i] = (double)p.E[bid * ZD + i];
    __syncthreads();
    for (int c = tid; c < G4; c += NT){
      const float* wr = p.Wih_a + (size_t)c * 768 + 512;
      double a = 0.0;
      for (int j = 0; j < 256; ++j) a = fma((double)wr[j], sz[j], a);
      p.E_proj_a64[(size_t)bid * G4 + c] = a;
    }
  } else if (bid < 128){     // E_proj_t (f32) row = bid-64
    const int ar = bid - 64;
    for (int i = tid; i < ZD; i += NT) sz[i] = (double)p.E[ar * ZD + i];
    __syncthreads();
    for (int c = tid; c < G4; c += NT){
      const float* wr = p.Wih_t + (size_t)c * 769 + 512;
      float a = 0.f;
      for (int j = 0; j < 256; ++j) a = fmaf(wr[j], (float)sz[j], a);
      p.E_proj_t[(size_t)ar * G4 + c] = a;
    }
  } else if (bid < 144){     // ts column of Wih_t
    int c = (bid - 128) * NT + tid;
    p.colt[c] = p.Wih_t[(size_t)c * 769 + 768];
  }
}

// ---------------- pre_a64 = t_rec @ Wih_a[:, :512]^T + biases (f64). grid 512: tm16 x tn32 ----------------
__global__ void __launch_bounds__(NT) k_preA(P p){
  __shared__ double st[16 * TD];   // 64 KB
  const int bid = blockIdx.x, tid = threadIdx.x;
  const int tm = bid >> 5, tn = bid & 31;
  const int rowb = tm * 16, colb = tn * 128;
  for (int idx = tid; idx < 16 * TD; idx += NT)
    st[idx] = p.t_rec64[(size_t)(rowb + (idx >> 9)) * TD + (idx & 511)];
  __syncthreads();
  const int rt = tid >> 4, c16 = tid & 15;
  const double* hr = st + rt * TD;
  for (int jj = 0; jj < 8; ++jj){
    const int col = colb + c16 * 8 + jj;
    const float* wr = p.Wih_a + (size_t)col * 768;
    double a = 0.0;
    for (int k = 0; k < TD; k += 4){
      a = fma((double)wr[k+0], hr[k+0], a); a = fma((double)wr[k+1], hr[k+1], a);
      a = fma((double)wr[k+2], hr[k+2], a); a = fma((double)wr[k+3], hr[k+3], a);
    }
    a += (double)p.bih_a[col] + (double)p.bhh_a[col];
    p.pre_a64[(size_t)(rowb + rt) * G4 + col] = a;
  }
}

// ---------------- pre_t = t_rec @ Wih_t[:, :512]^T + biases (f32). grid 256 ----------------
__global__ void __launch_bounds__(NT) k_preT(P p){
  __shared__ float st[32 * TD];   // 64 KB
  const int bid = blockIdx.x, tid = threadIdx.x;
  const int tm = bid >> 5, tn = bid & 31;
  const int rowb = tm * 32, colb = tn * 128;
  for (int idx = tid; idx < 32 * TD; idx += NT)
    st[idx] = p.t_rec32[(size_t)(rowb + (idx >> 9)) * TD + (idx & 511)];
  __syncthreads();
  const int rt = tid >> 3, c8 = tid & 7;
  const float* hr = st + rt * TD;
  for (int jj = 0; jj < 16; ++jj){
    const int col = colb + c8 * 16 + jj;
    const float* wr = p.Wih_t + (size_t)col * 769;
    float a = 0.f;
    for (int k = 0; k < TD; k += 4){
      a = fmaf(hr[k+0], wr[k+0], a); a = fmaf(hr[k+1], wr[k+1], a);
      a = fmaf(hr[k+2], wr[k+2], a); a = fmaf(hr[k+3], wr[k+3], a);
    }
    p.pre_t[(size_t)(rowb + rt) * G4 + col] = a + p.bih_t[col] + p.bhh_t[col];
  }
}

// ---------------- step A: LSTM-a recurrence (f64) + gacc_t (f32). grid 512 ----------------
__global__ void __launch_bounds__(NT) k_stepA(P p, int s){
  __shared__ __align__(16) char smraw[32768];
  const int bid = blockIdx.x, tid = threadIdx.x;
  const int sel = bid >> 8, b2 = bid & 255;
  const int x = b2 & 7, q = b2 >> 3;
  const int tc = x * 4 + (q & 3), tm = q >> 2;   // XCD-local cell-group -> Whh slice L2-resident
  const int rowb = tm * 32, cell0 = tc * 32;
  const int rd = s & 1, wrb = rd ^ 1;
  const int rt = tid >> 3, c8 = tid & 7;
  const int cell = cell0 + c8 * 4;
  const int row = rowb + rt;
  if (sel == 0){
    // ---- f64 path: gates_a = Whh_a . h_a ----
    double* sh = (double*)smraw;                 // 32 rows x 128 k
    const double* __restrict__ h = p.h_a64 + (size_t)rd * BB * CF;
    const float* __restrict__ W = p.Whh_a;
    const float* wp[4][4];
    #pragma unroll
    for (int g = 0; g < 4; ++g)
      #pragma unroll
      for (int j = 0; j < 4; ++j) wp[g][j] = W + (size_t)(g * CF + cell + j) * CF;
    double acc[4][4];
    #pragma unroll
    for (int g = 0; g < 4; ++g){ acc[g][0]=0; acc[g][1]=0; acc[g][2]=0; acc[g][3]=0; }
    for (int kb = 0; kb < CF; kb += 128){
      __syncthreads();
      for (int idx = tid; idx < 32 * 128; idx += NT)
        sh[idx] = h[(size_t)(rowb + (idx >> 7)) * CF + kb + (idx & 127)];
      __syncthreads();
      const double* hr = sh + rt * 128;
      for (int k = 0; k < 128; k += 4){
        double h0 = hr[k+0], h1 = hr[k+1], h2 = hr[k+2], h3 = hr[k+3];
        #pragma unroll
        for (int g = 0; g < 4; ++g){
          #pragma unroll
          for (int j = 0; j < 4; ++j){
            f32x4 w4 = *(const f32x4*)(wp[g][j] + kb + k);
            double a = acc[g][j];
            a = fma((double)w4[0], h0, a);
            a = fma((double)w4[1], h1, a);
            a = fma((double)w4[2], h2, a);
            a = fma((double)w4[3], h3, a);
            acc[g][j] = a;
          }
        }
      }
    }
    int idxv = p.idxb[row];
    idxv = idxv < 0 ? 0 : (idxv > 63 ? 63 : idxv);
    const double* pa = p.pre_a64 + (size_t)row * G4;
    const double* ea = p.E_proj_a64 + (size_t)idxv * G4;
    #pragma unroll
    for (int j = 0; j < 4; ++j){
      const int c = cell + j;
      double gi = acc[0][j] + pa[0*CF + c] + ea[0*CF + c];
      double gf = acc[1][j] + pa[1*CF + c] + ea[1*CF + c];
      double gg = acc[2][j] + pa[2*CF + c] + ea[2*CF + c];
      double go = acc[3][j] + pa[3*CF + c] + ea[3*CF + c];
      double cv = p.c_a64[(size_t)row * CF + c];
      double cn = sigd(gf) * cv + sigd(gi) * tanh(gg);
      double hn = sigd(go) * tanh(cn);
      p.c_a64[(size_t)row * CF + c] = cn;
      p.h_a64[(size_t)wrb * BB * CF + (size_t)row * CF + c] = hn;
    }
  } else {
    // ---- f32 path: gacc_t = pre_t + Whh_t . h_t ----
    float* sh = (float*)smraw;                   // 32 rows x 256 k
    const float* __restrict__ h = p.h_t + (size_t)rd * BB * CF;
    const float* __restrict__ W = p.Whh_t;
    float acc[4][4];
    #pragma unroll
    for (int g = 0; g < 4; ++g){ acc[g][0]=0; acc[g][1]=0; acc[g][2]=0; acc[g][3]=0; }
    for (int kb = 0; kb < CF; kb += 256){
      __syncthreads();
      for (int idx = tid; idx < 32 * 256; idx += NT)
        sh[idx] = h[(size_t)(rowb + (idx >> 8)) * CF + kb + (idx & 255)];
      __syncthreads();
      const float* hr = sh + rt * 256;
      for (int k = 0; k < 256; k += 4){
        f32x4 h4 = *(const f32x4*)(hr + k);
        #pragma unroll
        for (int g = 0; g < 4; ++g){
          #pragma unroll
          for (int j = 0; j < 4; ++j){
            f32x4 w4 = *(const f32x4*)(W + (size_t)(g * CF + cell + j) * CF + kb + k);
            acc[g][j] += fmaf(h4[0], w4[0], fmaf(h4[1], w4[1], fmaf(h4[2], w4[2], h4[3] * w4[3])));
          }
        }
      }
    }
    const float* pt = p.pre_t + (size_t)row * G4;
    float* gt = p.gacc_t + (size_t)row * G4;
    #pragma unroll
    for (int g = 0; g < 4; ++g)
      #pragma unroll
      for (int j = 0; j < 4; ++j)
        gt[g*CF + cell + j] = acc[g][j] + pt[g*CF + cell + j];
  }
}

// ---------------- step B: f64 logits/argmax/softmax + f32 LSTM-t pointwise ----------------
__global__ void __launch_bounds__(NT) k_stepB(P p, int s){
  __shared__ double shd[1092];
  const int b = blockIdx.x, tid = threadIdx.x;
  const int cur = (s + 1) & 1;   // current h_a buffer; also h_t write buffer
  for (int i = tid; i < CF; i += NT) shd[i] = p.h_a64[(size_t)cur * BB * CF + (size_t)b * CF + i];
  if (tid == 0) shd[1088] = (s == 0) ? 0.0 : ((double)p.ts_accum[b] + (double)p.b_ts2[0]);
  __syncthreads();
  {
    const int w = tid >> 6, l = tid & 63, l15 = l & 15, quad = l >> 4;
    const int a = w * 16 + l15;
    const float* wr = p.W_act + (size_t)a * CF + quad * 256;
    const double* hp = shd + quad * 256;
    double acc = 0.0;
    for (int kk = 0; kk < 256; kk += 4){
      acc = fma((double)wr[kk+0], hp[kk+0], acc);
      acc = fma((double)wr[kk+1], hp[kk+1], acc);
      acc = fma((double)wr[kk+2], hp[kk+2], acc);
      acc = fma((double)wr[kk+3], hp[kk+3], acc);
    }
    acc += __shfl_xor(acc, 16, 64);
    acc += __shfl_xor(acc, 32, 64);
    if (quad == 0) shd[1024 + a] = acc;
  }
  __syncthreads();
  if (tid < 64){
    double acc = shd[1024 + tid] + (double)p.b_act[tid];
    double m = acc;
    #pragma unroll
    for (int off = 32; off; off >>= 1) m = fmax(m, __shfl_xor(m, off, 64));
    unsigned long long ball = __ballot(acc == m);
    int idxv = __ffsll(ball) - 1;               // first max == np.argmax
    idxv = idxv < 0 ? 0 : (idxv > 63 ? 63 : idxv);
    double e = exp(acc - m);
    double ssum = e;
    #pragma unroll
    for (int off = 32; off; off >>= 1) ssum += __shfl_xor(ssum, off, 64);
    p.out[(size_t)b * (NSTEP * NA) + s * NA + tid] = (float)(e / ssum);
    if (tid == 0){
      p.idxb[b] = idxv;
      shd[1089] = (double)idxv;
      if (s > 0) p.out[TS_OFF + b * NSTEP + (s - 1)] = (float)shd[1088];
    }
  }
  __syncthreads();
  const float ts_val = (float)shd[1088];
  const int idxv = (int)shd[1089];
  const int c0 = tid * 4;
  const float* gb = p.gacc_t   + (size_t)b * G4;
  const float* eb = p.E_proj_t + (size_t)idxv * G4;
  f32x4 gi = *(const f32x4*)(gb + 0*CF + c0) + *(const f32x4*)(eb + 0*CF + c0) + ts_val * *(const f32x4*)(p.colt + 0*CF + c0);
  f32x4 gf = *(const f32x4*)(gb + 1*CF + c0) + *(const f32x4*)(eb + 1*CF + c0) + ts_val * *(const f32x4*)(p.colt + 1*CF + c0);
  f32x4 gg = *(const f32x4*)(gb + 2*CF + c0) + *(const f32x4*)(eb + 2*CF + c0) + ts_val * *(const f32x4*)(p.colt + 2*CF + c0);
  f32x4 go = *(const f32x4*)(gb + 3*CF + c0) + *(const f32x4*)(eb + 3*CF + c0) + ts_val * *(const f32x4*)(p.colt + 3*CF + c0);
  f32x4 cv = *(f32x4*)(p.c_t + (size_t)b * CF + c0);
  f32x4 cn, hn;
  #pragma unroll
  for (int j = 0; j < 4; ++j){
    float cj = sigf(gf[j]) * cv[j] + sigf(gi[j]) * tanhf_(gg[j]);
    float hj = sigf(go[j]) * tanhf_(cj);
    cn[j] = cj; hn[j] = hj;
  }
  *(f32x4*)(p.c_t + (size_t)b * CF + c0) = cn;
  *(f32x4*)(p.h_t + (size_t)cur * BB * CF + (size_t)b * CF + c0) = hn;
  __syncthreads();
  if (tid == 0) p.ts_accum[b] = 0.f;   // ready for this step's tshead accumulation
}

// ---------------- ts head: ts_accum[row] += partials of w2 . relu(W_ts1 h_t + b1) ----------------
__global__ void __launch_bounds__(NT) k_tshead(P p, int s){
  __shared__ __align__(16) float sh[32 * 256];
  const int bid = blockIdx.x, tid = threadIdx.x;
  const int tm = bid >> 4, tj = bid & 15;
  const int rowb = tm * 32;
  const float* __restrict__ h = p.h_t + (size_t)((s + 1) & 1) * BB * CF;
  const int rt = tid >> 3, j8 = tid & 7;
  float acc[4] = {0.f, 0.f, 0.f, 0.f};
  for (int kb = 0; kb < CF; kb += 256){
    __syncthreads();
    for (int idx = tid; idx < 32 * 256; idx += NT)
      sh[idx] = h[(size_t)(rowb + (idx >> 8)) * CF + kb + (idx & 255)];
    __syncthreads();
    const float* hr = sh + rt * 256;
    for (int k = 0; k < 256; k += 4){
      f32x4 h4 = *(const f32x4*)(hr + k);
      #pragma unroll
      for (int jj = 0; jj < 4; ++jj){
        const int j = tj * 32 + j8 * 4 + jj;
        f32x4 w4 = *(const f32x4*)(p.W_ts1 + (size_t)j * CF + kb + k);
        acc[jj] += fmaf(h4[0], w4[0], fmaf(h4[1], w4[1], fmaf(h4[2], w4[2], h4[3] * w4[3])));
      }
    }
  }
  float v = 0.f;
  #pragma unroll
  for (int jj = 0; jj < 4; ++jj){
    const int j = tj * 32 + j8 * 4 + jj;
    float t = acc[jj] + p.b_ts1[j];
    v += (t > 0.f ? t : 0.f) * p.W_ts2[j];
  }
  v += __shfl_xor(v, 1, 64);
  v += __shfl_xor(v, 2, 64);
  v += __shfl_xor(v, 4, 64);
  if (j8 == 0) atomicAdd(p.ts_accum + rowb + rt, v);
}

__global__ void __launch_bounds__(NT) k_tswrite(P p){
  p.out[TS_OFF + threadIdx.x * NSTEP + 63] = p.ts_accum[threadIdx.x] + p.b_ts2[0];
}

extern "C" void kernel_launch(void* const* d_in, const int* in_sizes, int n_in,
                              void* d_out, int out_size, void* d_ws, size_t ws_size,
                              hipStream_t stream){
  (void)in_sizes; (void)n_in; (void)out_size; (void)ws_size;
  P p;
  p.z     = (const float*)d_in[0];  p.W_z2t = (const float*)d_in[1];  p.b_z2t = (const float*)d_in[2];
  p.E     = (const float*)d_in[3];  p.Wih_a = (const float*)d_in[4];  p.Whh_a = (const float*)d_in[5];
  p.bih_a = (const float*)d_in[6];  p.bhh_a = (const float*)d_in[7];  p.Wih_t = (const float*)d_in[8];
  p.Whh_t = (const float*)d_in[9];  p.bih_t = (const float*)d_in[10]; p.bhh_t = (const float*)d_in[11];
  p.W_act = (const float*)d_in[12]; p.b_act = (const float*)d_in[13]; p.W_ts1 = (const float*)d_in[14];
  p.b_ts1 = (const float*)d_in[15]; p.W_ts2 = (const float*)d_in[16]; p.b_ts2 = (const float*)d_in[17];
  p.out = (float*)d_out;
  char* w = (char*)d_ws;
  size_t off = 0;
  auto alloc = [&](size_t bytes) -> void* { void* r = w + off; off += (bytes + 255) & ~(size_t)255; return r; };
  p.t_rec64    = (double*)alloc((size_t)BB * TD * 8);
  p.pre_a64    = (double*)alloc((size_t)BB * G4 * 8);
  p.E_proj_a64 = (double*)alloc((size_t)NA * G4 * 8);
  p.h_a64      = (double*)alloc((size_t)2 * BB * CF * 8);
  p.c_a64      = (double*)alloc((size_t)BB * CF * 8);
  p.t_rec32    = (float*)alloc((size_t)BB * TD * 4);
  p.pre_t      = (float*)alloc((size_t)BB * G4 * 4);
  p.E_proj_t   = (float*)alloc((size_t)NA * G4 * 4);
  p.colt       = (float*)alloc((size_t)G4 * 4);
  p.h_t        = (float*)alloc((size_t)2 * BB * CF * 4);
  p.c_t        = (float*)alloc((size_t)BB * CF * 4);
  p.gacc_t     = (float*)alloc((size_t)BB * G4 * 4);
  p.ts_accum   = (float*)alloc((size_t)BB * 4);
  p.idxb       = (int*)  alloc((size_t)BB * 4);

  k_setup<<<dim3(256), dim3(NT), 0, stream>>>(p);
  k_preA <<<dim3(512), dim3(NT), 0, stream>>>(p);
  k_preT <<<dim3(256), dim3(NT), 0, stream>>>(p);
  for (int s = 0; s < NSTEP; ++s){
    k_stepA <<<dim3(512), dim3(NT), 0, stream>>>(p, s);
    k_stepB <<<dim3(256), dim3(NT), 0, stream>>>(p, s);
    k_tshead<<<dim3(128), dim3(NT), 0, stream>>>(p, s);
  }
  k_tswrite<<<dim3(1), dim3(NT), 0, stream>>>(p);
}

// Round 8
// 16340.202 us; speedup vs baseline: 4.3605x; 4.3605x over previous
//
#include <hip/hip_runtime.h>
#include <stdint.h>

typedef unsigned int u32;
typedef float  f32x4 __attribute__((ext_vector_type(4)));

constexpr int NT = 256;   // threads per block
constexpr int BB = 256;   // batch
constexpr int ZD = 256;
constexpr int TD = 512;
constexpr int CF = 1024;
constexpr int G4 = 4096;
constexpr int NA = 64;
constexpr int NSTEP = 64;
constexpr int TS_OFF = BB * NSTEP * NA;   // acts [256][64][64] then ts [256][64]

struct P {
  const float *z, *W_z2t, *b_z2t, *E, *Wih_a, *Whh_a, *bih_a, *bhh_a,
              *Wih_t, *Whh_t, *bih_t, *bhh_t, *W_act, *b_act, *W_ts1, *b_ts1, *W_ts2, *b_ts2;
  float* out;                                               // float32 output (ref dtype)
  // f64 argmax-critical path
  double *t_rec64, *pre_a64, *E_proj_a64, *h_a64, *c_a64, *gacc_a;  // h_a64 dbuf [2][256][1024]
  // f32 ts path
  float *t_rec32, *pre_t, *E_proj_t, *colt, *h_t, *c_t, *gacc_t, *ts_accum;  // h_t dbuf [2][..]
  int* idxb;
};

__device__ __forceinline__ float sigf(float x){ return 1.f / (1.f + expf(-x)); }
__device__ __forceinline__ float tanhf_(float x){
  float ax = fabsf(x); float e = expf(-2.f * ax);
  float t = 1.f - 2.f * e / (1.f + e);
  return x < 0.f ? -t : t;
}
__device__ __forceinline__ double sigd(double x){ return 1.0 / (1.0 + exp(-x)); }

// ---------------- setup: t_rec (f64+f32), E_proj tables, colt, state init ----------------
__global__ void __launch_bounds__(NT) k_setup(P p){
  __shared__ double sz[ZD];
  const int bid = blockIdx.x, tid = threadIdx.x;
  for (int i = tid; i < ZD; i += NT) sz[i] = (double)p.z[bid * ZD + i];
  __syncthreads();
  for (int k = tid; k < TD; k += NT){
    const float* wr = p.W_z2t + (size_t)k * ZD;
    double a = 0.0;
    for (int j = 0; j < ZD; ++j) a = fma((double)wr[j], sz[j], a);
    a += (double)p.b_z2t[k];
    double t = a > 0.0 ? a : 0.0;
    p.t_rec64[(size_t)bid * TD + k] = t;
    p.t_rec32[(size_t)bid * TD + k] = (float)t;
  }
  for (int i = tid; i < CF; i += NT){
    p.c_a64[(size_t)bid * CF + i] = 0.0;
    p.h_a64[(size_t)bid * CF + i] = 0.0;  // buffer 0
    p.c_t[(size_t)bid * CF + i] = 0.f;
    p.h_t[(size_t)bid * CF + i] = 0.f;    // buffer 0
  }
  if (tid == 0){ p.idxb[bid] = NA - 1; p.ts_accum[bid] = 0.f; }
  __syncthreads();
  if (bid < 64){             // E_proj_a64 row = bid: E[bid] . Wih_a[col, 512:768]
    for (int i = tid; i < ZD; i += NT) sz[i] = (double)p.E[bid * ZD + i];
    __syncthreads();
    for (int c = tid; c < G4; c += NT){
      const float* wr = p.Wih_a + (size_t)c * 768 + 512;
      double a = 0.0;
      for (int j = 0; j < 256; ++j) a = fma((double)wr[j], sz[j], a);
      p.E_proj_a64[(size_t)bid * G4 + c] = a;
    }
  } else if (bid < 128){     // E_proj_t (f32) row = bid-64
    const int ar = bid - 64;
    for (int i = tid; i < ZD; i += NT) sz[i] = (double)p.E[ar * ZD + i];
    __syncthreads();
    for (int c = tid; c < G4; c += NT){
      const float* wr = p.Wih_t + (size_t)c * 769 + 512;
      float a = 0.f;
      for (int j = 0; j < 256; ++j) a = fmaf(wr[j], (float)sz[j], a);
      p.E_proj_t[(size_t)ar * G4 + c] = a;
    }
  } else if (bid < 144){     // ts column of Wih_t
    int c = (bid - 128) * NT + tid;
    p.colt[c] = p.Wih_t[(size_t)c * 769 + 768];
  }
}

// ---------------- pre_a64 = t_rec @ Wih_a[:, :512]^T + biases (f64). grid 512 ----------------
__global__ void __launch_bounds__(NT) k_preA(P p){
  __shared__ double st[16 * TD];   // 64 KB
  const int bid = blockIdx.x, tid = threadIdx.x;
  const int tm = bid >> 5, tn = bid & 31;
  const int rowb = tm * 16, colb = tn * 128;
  for (int idx = tid; idx < 16 * TD; idx += NT)
    st[idx] = p.t_rec64[(size_t)(rowb + (idx >> 9)) * TD + (idx & 511)];
  __syncthreads();
  const int rt = tid >> 4, c16 = tid & 15;
  const double* hr = st + rt * TD;
  for (int jj = 0; jj < 8; ++jj){
    const int col = colb + c16 * 8 + jj;
    const float* wr = p.Wih_a + (size_t)col * 768;
    double a = 0.0;
    for (int k = 0; k < TD; k += 4){
      a = fma((double)wr[k+0], hr[k+0], a); a = fma((double)wr[k+1], hr[k+1], a);
      a = fma((double)wr[k+2], hr[k+2], a); a = fma((double)wr[k+3], hr[k+3], a);
    }
    a += (double)p.bih_a[col] + (double)p.bhh_a[col];
    p.pre_a64[(size_t)(rowb + rt) * G4 + col] = a;
  }
}

// ---------------- pre_t = t_rec @ Wih_t[:, :512]^T + biases (f32). grid 256 ----------------
__global__ void __launch_bounds__(NT) k_preT(P p){
  __shared__ float st[32 * TD];   // 64 KB
  const int bid = blockIdx.x, tid = threadIdx.x;
  const int tm = bid >> 5, tn = bid & 31;
  const int rowb = tm * 32, colb = tn * 128;
  for (int idx = tid; idx < 32 * TD; idx += NT)
    st[idx] = p.t_rec32[(size_t)(rowb + (idx >> 9)) * TD + (idx & 511)];
  __syncthreads();
  const int rt = tid >> 3, c8 = tid & 7;
  const float* hr = st + rt * TD;
  for (int jj = 0; jj < 16; ++jj){
    const int col = colb + c8 * 16 + jj;
    const float* wr = p.Wih_t + (size_t)col * 769;
    float a = 0.f;
    for (int k = 0; k < TD; k += 4){
      a = fmaf(hr[k+0], wr[k+0], a); a = fmaf(hr[k+1], wr[k+1], a);
      a = fmaf(hr[k+2], wr[k+2], a); a = fmaf(hr[k+3], wr[k+3], a);
    }
    p.pre_t[(size_t)(rowb + rt) * G4 + col] = a + p.bih_t[col] + p.bhh_t[col];
  }
}

// ---------------- fused ts head body (f32): ts_accum += partials, for step with h buffer hbuf ----------------
__device__ void tshead_body(const P& p, float* sh, int bid, int hbuf){
  const int tid = threadIdx.x;
  const int tm = bid >> 4, tj = bid & 15;
  const int rowb = tm * 32;
  const float* __restrict__ h = p.h_t + (size_t)hbuf * BB * CF;
  const int rt = tid >> 3, j8 = tid & 7;
  float acc[4] = {0.f, 0.f, 0.f, 0.f};
  for (int kb = 0; kb < CF; kb += 256){
    __syncthreads();
    for (int idx = tid; idx < 32 * 256; idx += NT)
      sh[idx] = h[(size_t)(rowb + (idx >> 8)) * CF + kb + (idx & 255)];
    __syncthreads();
    const float* hr = sh + rt * 256;
    for (int k = 0; k < 256; k += 4){
      f32x4 h4 = *(const f32x4*)(hr + k);
      #pragma unroll
      for (int jj = 0; jj < 4; ++jj){
        const int j = tj * 32 + j8 * 4 + jj;
        f32x4 w4 = *(const f32x4*)(p.W_ts1 + (size_t)j * CF + kb + k);
        acc[jj] += fmaf(h4[0], w4[0], fmaf(h4[1], w4[1], fmaf(h4[2], w4[2], h4[3] * w4[3])));
      }
    }
  }
  float v = 0.f;
  #pragma unroll
  for (int jj = 0; jj < 4; ++jj){
    const int j = tj * 32 + j8 * 4 + jj;
    float t = acc[jj] + p.b_ts1[j];
    v += (t > 0.f ? t : 0.f) * p.W_ts2[j];
  }
  v += __shfl_xor(v, 1, 64);
  v += __shfl_xor(v, 2, 64);
  v += __shfl_xor(v, 4, 64);
  if (j8 == 0) atomicAdd(p.ts_accum + rowb + rt, v);
}

// ---------------- step A: tiled GEMMs. grid 640: 512 GEMM tiles + 128 tshead(s-1) ----------------
// GEMM tile: 64 rows x 64 gate-cols, LDS-staged A and B, 4x4 register micro-tile per thread.
__global__ void __launch_bounds__(NT) k_stepA(P p, int s){
  __shared__ float smem[17408];   // 69.6 KB
  const int bid = blockIdx.x, tid = threadIdx.x;
  if (bid >= 512){                 // fused ts head for step s-1
    if (s == 0) return;
    tshead_body(p, smem, bid - 512, s & 1);
    return;
  }
  const int xcd = bid & 7, i = bid >> 3;
  const int sel = i & 1, j = i >> 1;
  const int rowtile = j & 3, colgroup = j >> 2;
  const int coltile = colgroup * 8 + xcd;      // stable col->XCD map: Whh slice L2-resident
  const int rowb = rowtile * 64, colb = coltile * 64;
  const int rd = s & 1;
  const int tr = tid & 15, tc = tid >> 4;      // 4 rows x 4 cols micro-tile
  const int rr = tid >> 2, kq = tid & 3;       // staging map
  if (sel == 0){
    // ---- f64 path: gacc_a = h_a64 @ Whh_a^T + pre_a64 (bit-compatible with R7 numerics) ----
    double* Ash = (double*)smem;               // [64][66] doubles (33.8 KB)
    float*  Bsh = smem + 8448;                 // [64][68] floats  (17.4 KB)
    const double* __restrict__ hA = p.h_a64 + (size_t)rd * BB * CF;
    const float* __restrict__ W = p.Whh_a;
    double acc[4][4] = {};
    for (int kb = 0; kb < CF; kb += 64){
      __syncthreads();
      {
        const double* src  = hA + (size_t)(rowb + rr) * CF + kb + kq * 16;
        const float*  wsrc = W  + (size_t)(colb + rr) * CF + kb + kq * 16;
        #pragma unroll
        for (int kk = 0; kk < 16; ++kk){
          Ash[(kq * 16 + kk) * 66 + rr] = src[kk];
          Bsh[(kq * 16 + kk) * 68 + rr] = wsrc[kk];
        }
      }
      __syncthreads();
      #pragma unroll 2
      for (int k = 0; k < 64; ++k){
        const double* ap = Ash + k * 66 + 4 * tr;
        double a0 = ap[0], a1 = ap[1], a2 = ap[2], a3 = ap[3];
        f32x4 bf = *(const f32x4*)(Bsh + k * 68 + 4 * tc);
        double b0 = (double)bf[0], b1 = (double)bf[1], b2 = (double)bf[2], b3 = (double)bf[3];
        acc[0][0] = fma(a0, b0, acc[0][0]); acc[0][1] = fma(a0, b1, acc[0][1]);
        acc[0][2] = fma(a0, b2, acc[0][2]); acc[0][3] = fma(a0, b3, acc[0][3]);
        acc[1][0] = fma(a1, b0, acc[1][0]); acc[1][1] = fma(a1, b1, acc[1][1]);
        acc[1][2] = fma(a1, b2, acc[1][2]); acc[1][3] = fma(a1, b3, acc[1][3]);
        acc[2][0] = fma(a2, b0, acc[2][0]); acc[2][1] = fma(a2, b1, acc[2][1]);
        acc[2][2] = fma(a2, b2, acc[2][2]); acc[2][3] = fma(a2, b3, acc[2][3]);
        acc[3][0] = fma(a3, b0, acc[3][0]); acc[3][1] = fma(a3, b1, acc[3][1]);
        acc[3][2] = fma(a3, b2, acc[3][2]); acc[3][3] = fma(a3, b3, acc[3][3]);
      }
    }
    #pragma unroll
    for (int ii = 0; ii < 4; ++ii){
      const int row = rowb + 4 * tr + ii;
      #pragma unroll
      for (int jj = 0; jj < 4; ++jj){
        const int gcol = colb + 4 * tc + jj;
        p.gacc_a[(size_t)row * G4 + gcol] = acc[ii][jj] + p.pre_a64[(size_t)row * G4 + gcol];
      }
    }
  } else {
    // ---- f32 path: gacc_t = h_t @ Whh_t^T + pre_t ----
    float* Ash = smem;                          // [128][68]
    float* Bsh = smem + 8704;                   // [128][68]
    const float* __restrict__ hA = p.h_t + (size_t)rd * BB * CF;
    const float* __restrict__ W = p.Whh_t;
    float acc[4][4] = {};
    for (int kb = 0; kb < CF; kb += 128){
      __syncthreads();
      {
        const float* src  = hA + (size_t)(rowb + rr) * CF + kb + kq * 32;
        const float* wsrc = W  + (size_t)(colb + rr) * CF + kb + kq * 32;
        #pragma unroll
        for (int kk = 0; kk < 32; ++kk){
          Ash[(kq * 32 + kk) * 68 + rr] = src[kk];
          Bsh[(kq * 32 + kk) * 68 + rr] = wsrc[kk];
        }
      }
      __syncthreads();
      #pragma unroll 4
      for (int k = 0; k < 128; ++k){
        f32x4 a = *(const f32x4*)(Ash + k * 68 + 4 * tr);
        f32x4 b = *(const f32x4*)(Bsh + k * 68 + 4 * tc);
        #pragma unroll
        for (int ii = 0; ii < 4; ++ii)
          #pragma unroll
          for (int jj = 0; jj < 4; ++jj)
            acc[ii][jj] = fmaf(a[ii], b[jj], acc[ii][jj]);
      }
    }
    #pragma unroll
    for (int ii = 0; ii < 4; ++ii){
      const int row = rowb + 4 * tr + ii;
      #pragma unroll
      for (int jj = 0; jj < 4; ++jj){
        const int gcol = colb + 4 * tc + jj;
        p.gacc_t[(size_t)row * G4 + gcol] = acc[ii][jj] + p.pre_t[(size_t)row * G4 + gcol];
      }
    }
  }
}

// ---------------- step B: LSTM-a pointwise (f64) + logits/argmax/softmax (f64) + LSTM-t (f32) ----------------
__global__ void __launch_bounds__(NT) k_stepB(P p, int s){
  __shared__ double shd[1092];
  const int b = blockIdx.x, tid = threadIdx.x;
  const int cur = (s + 1) & 1;   // h_a/h_t write buffer
  int idxp = p.idxb[b];
  idxp = idxp < 0 ? 0 : (idxp > 63 ? 63 : idxp);
  // LSTM-a pointwise: 4 cells per thread
  {
    const double* ga = p.gacc_a + (size_t)b * G4;       // includes pre_a (biases folded)
    const double* ea = p.E_proj_a64 + (size_t)idxp * G4;
    const int c0 = tid * 4;
    #pragma unroll
    for (int jj = 0; jj < 4; ++jj){
      const int c = c0 + jj;
      double gi = ga[0*CF + c] + ea[0*CF + c];
      double gf = ga[1*CF + c] + ea[1*CF + c];
      double gg = ga[2*CF + c] + ea[2*CF + c];
      double go = ga[3*CF + c] + ea[3*CF + c];
      double cv = p.c_a64[(size_t)b * CF + c];
      double cn = sigd(gf) * cv + sigd(gi) * tanh(gg);
      double hn = sigd(go) * tanh(cn);
      p.c_a64[(size_t)b * CF + c] = cn;
      p.h_a64[(size_t)cur * BB * CF + (size_t)b * CF + c] = hn;
      shd[c] = hn;
    }
  }
  if (tid == 0) shd[1088] = (s == 0) ? 0.0 : ((double)p.ts_accum[b] + (double)p.b_ts2[0]);
  __syncthreads();
  {
    const int w = tid >> 6, l = tid & 63, l15 = l & 15, quad = l >> 4;
    const int a = w * 16 + l15;
    const float* wr = p.W_act + (size_t)a * CF + quad * 256;
    const double* hp = shd + quad * 256;
    double acc = 0.0;
    for (int kk = 0; kk < 256; kk += 4){
      acc = fma((double)wr[kk+0], hp[kk+0], acc);
      acc = fma((double)wr[kk+1], hp[kk+1], acc);
      acc = fma((double)wr[kk+2], hp[kk+2], acc);
      acc = fma((double)wr[kk+3], hp[kk+3], acc);
    }
    acc += __shfl_xor(acc, 16, 64);
    acc += __shfl_xor(acc, 32, 64);
    if (quad == 0) shd[1024 + a] = acc;
  }
  __syncthreads();
  if (tid < 64){
    double acc = shd[1024 + tid] + (double)p.b_act[tid];
    double m = acc;
    #pragma unroll
    for (int off = 32; off; off >>= 1) m = fmax(m, __shfl_xor(m, off, 64));
    unsigned long long ball = __ballot(acc == m);
    int idxv = __ffsll(ball) - 1;               // first max == np.argmax
    idxv = idxv < 0 ? 0 : (idxv > 63 ? 63 : idxv);
    double e = exp(acc - m);
    double ssum = e;
    #pragma unroll
    for (int off = 32; off; off >>= 1) ssum += __shfl_xor(ssum, off, 64);
    p.out[(size_t)b * (NSTEP * NA) + s * NA + tid] = (float)(e / ssum);
    if (tid == 0){
      p.idxb[b] = idxv;
      shd[1089] = (double)idxv;
      if (s > 0) p.out[TS_OFF + b * NSTEP + (s - 1)] = (float)shd[1088];
    }
  }
  __syncthreads();
  const float ts_val = (float)shd[1088];
  const int idxv = (int)shd[1089];
  const int c0 = tid * 4;
  const float* gb = p.gacc_t   + (size_t)b * G4;   // includes pre_t (biases folded)
  const float* eb = p.E_proj_t + (size_t)idxv * G4;
  f32x4 gi = *(const f32x4*)(gb + 0*CF + c0) + *(const f32x4*)(eb + 0*CF + c0) + ts_val * *(const f32x4*)(p.colt + 0*CF + c0);
  f32x4 gf = *(const f32x4*)(gb + 1*CF + c0) + *(const f32x4*)(eb + 1*CF + c0) + ts_val * *(const f32x4*)(p.colt + 1*CF + c0);
  f32x4 gg = *(const f32x4*)(gb + 2*CF + c0) + *(const f32x4*)(eb + 2*CF + c0) + ts_val * *(const f32x4*)(p.colt + 2*CF + c0);
  f32x4 go = *(const f32x4*)(gb + 3*CF + c0) + *(const f32x4*)(eb + 3*CF + c0) + ts_val * *(const f32x4*)(p.colt + 3*CF + c0);
  f32x4 cv = *(f32x4*)(p.c_t + (size_t)b * CF + c0);
  f32x4 cn, hn;
  #pragma unroll
  for (int jj = 0; jj < 4; ++jj){
    float cj = sigf(gf[jj]) * cv[jj] + sigf(gi[jj]) * tanhf_(gg[jj]);
    float hj = sigf(go[jj]) * tanhf_(cj);
    cn[jj] = cj; hn[jj] = hj;
  }
  *(f32x4*)(p.c_t + (size_t)b * CF + c0) = cn;
  *(f32x4*)(p.h_t + (size_t)cur * BB * CF + (size_t)b * CF + c0) = hn;
  __syncthreads();
  if (tid == 0) p.ts_accum[b] = 0.f;   // ready for next step's tshead accumulation
}

// final ts head for step 63 (h_t buffer 0) + write
__global__ void __launch_bounds__(NT) k_tsfin(P p){
  __shared__ float sh[32 * 256];
  tshead_body(p, sh, blockIdx.x, 0);
}
__global__ void __launch_bounds__(NT) k_tswrite(P p){
  p.out[TS_OFF + threadIdx.x * NSTEP + 63] = p.ts_accum[threadIdx.x] + p.b_ts2[0];
}

extern "C" void kernel_launch(void* const* d_in, const int* in_sizes, int n_in,
                              void* d_out, int out_size, void* d_ws, size_t ws_size,
                              hipStream_t stream){
  (void)in_sizes; (void)n_in; (void)out_size; (void)ws_size;
  P p;
  p.z     = (const float*)d_in[0];  p.W_z2t = (const float*)d_in[1];  p.b_z2t = (const float*)d_in[2];
  p.E     = (const float*)d_in[3];  p.Wih_a = (const float*)d_in[4];  p.Whh_a = (const float*)d_in[5];
  p.bih_a = (const float*)d_in[6];  p.bhh_a = (const float*)d_in[7];  p.Wih_t = (const float*)d_in[8];
  p.Whh_t = (const float*)d_in[9];  p.bih_t = (const float*)d_in[10]; p.bhh_t = (const float*)d_in[11];
  p.W_act = (const float*)d_in[12]; p.b_act = (const float*)d_in[13]; p.W_ts1 = (const float*)d_in[14];
  p.b_ts1 = (const float*)d_in[15]; p.W_ts2 = (const float*)d_in[16]; p.b_ts2 = (const float*)d_in[17];
  p.out = (float*)d_out;
  char* w = (char*)d_ws;
  size_t off = 0;
  auto alloc = [&](size_t bytes) -> void* { void* r = w + off; off += (bytes + 255) & ~(size_t)255; return r; };
  p.t_rec64    = (double*)alloc((size_t)BB * TD * 8);
  p.pre_a64    = (double*)alloc((size_t)BB * G4 * 8);
  p.E_proj_a64 = (double*)alloc((size_t)NA * G4 * 8);
  p.h_a64      = (double*)alloc((size_t)2 * BB * CF * 8);
  p.c_a64      = (double*)alloc((size_t)BB * CF * 8);
  p.gacc_a     = (double*)alloc((size_t)BB * G4 * 8);
  p.t_rec32    = (float*)alloc((size_t)BB * TD * 4);
  p.pre_t      = (float*)alloc((size_t)BB * G4 * 4);
  p.E_proj_t   = (float*)alloc((size_t)NA * G4 * 4);
  p.colt       = (float*)alloc((size_t)G4 * 4);
  p.h_t        = (float*)alloc((size_t)2 * BB * CF * 4);
  p.c_t        = (float*)alloc((size_t)BB * CF * 4);
  p.gacc_t     = (float*)alloc((size_t)BB * G4 * 4);
  p.ts_accum   = (float*)alloc((size_t)BB * 4);
  p.idxb       = (int*)  alloc((size_t)BB * 4);

  k_setup<<<dim3(256), dim3(NT), 0, stream>>>(p);
  k_preA <<<dim3(512), dim3(NT), 0, stream>>>(p);
  k_preT <<<dim3(256), dim3(NT), 0, stream>>>(p);
  for (int s = 0; s < NSTEP; ++s){
    k_stepA<<<dim3(640), dim3(NT), 0, stream>>>(p, s);
    k_stepB<<<dim3(256), dim3(NT), 0, stream>>>(p, s);
  }
  k_tsfin  <<<dim3(128), dim3(NT), 0, stream>>>(p);
  k_tswrite<<<dim3(1),   dim3(NT), 0, stream>>>(p);
}

// Round 9
// 14700.273 us; speedup vs baseline: 4.8469x; 1.1116x over previous
//
#include <hip/hip_runtime.h>
#include <stdint.h>

typedef unsigned int u32;
typedef float  f32x4 __attribute__((ext_vector_type(4)));
typedef float  f32x2 __attribute__((ext_vector_type(2)));
typedef double f64x2 __attribute__((ext_vector_type(2)));

constexpr int NT = 256;   // threads per block
constexpr int BB = 256;   // batch
constexpr int ZD = 256;
constexpr int TD = 512;
constexpr int CF = 1024;
constexpr int G4 = 4096;
constexpr int NA = 64;
constexpr int NSTEP = 64;
constexpr int TS_OFF = BB * NSTEP * NA;   // acts [256][64][64] then ts [256][64]

struct P {
  const float *z, *W_z2t, *b_z2t, *E, *Wih_a, *Whh_a, *bih_a, *bhh_a,
              *Wih_t, *Whh_t, *bih_t, *bhh_t, *W_act, *b_act, *W_ts1, *b_ts1, *W_ts2, *b_ts2;
  float* out;                                               // float32 output (ref dtype)
  // f64 argmax-critical path
  double *t_rec64, *pre_a64, *E_proj_a64, *h_a64, *c_a64, *gacc_a;  // h_a64 dbuf [2][256][1024]
  // f32 ts path
  float *t_rec32, *pre_t, *E_proj_t, *colt, *h_t, *c_t, *gacc_t, *ts_accum;  // h_t dbuf [2][..]
  int* idxb;
};

__device__ __forceinline__ float sigf(float x){ return 1.f / (1.f + expf(-x)); }
__device__ __forceinline__ float tanhf_(float x){
  float ax = fabsf(x); float e = expf(-2.f * ax);
  float t = 1.f - 2.f * e / (1.f + e);
  return x < 0.f ? -t : t;
}
__device__ __forceinline__ double sigd(double x){ return 1.0 / (1.0 + exp(-x)); }

// ---------------- setup: t_rec (f64+f32), state init ----------------
__global__ void __launch_bounds__(NT) k_setup(P p){
  __shared__ double sz[ZD];
  const int bid = blockIdx.x, tid = threadIdx.x;
  for (int i = tid; i < ZD; i += NT) sz[i] = (double)p.z[bid * ZD + i];
  __syncthreads();
  for (int k = tid; k < TD; k += NT){
    const float* wr = p.W_z2t + (size_t)k * ZD;
    double a = 0.0;
    for (int j = 0; j < ZD; ++j) a = fma((double)wr[j], sz[j], a);
    a += (double)p.b_z2t[k];
    double t = a > 0.0 ? a : 0.0;
    p.t_rec64[(size_t)bid * TD + k] = t;
    p.t_rec32[(size_t)bid * TD + k] = (float)t;
  }
  for (int i = tid; i < CF; i += NT){
    p.c_a64[(size_t)bid * CF + i] = 0.0;
    p.h_a64[(size_t)bid * CF + i] = 0.0;  // buffer 0
    p.c_t[(size_t)bid * CF + i] = 0.f;
    p.h_t[(size_t)bid * CF + i] = 0.f;    // buffer 0
  }
  if (tid == 0){ p.idxb[bid] = NA - 1; p.ts_accum[bid] = 0.f; }
}

// ---------------- E_proj tables + colt. grid 528 ----------------
__global__ void __launch_bounds__(NT) k_eproj(P p){
  __shared__ double sz[ZD];
  const int bid = blockIdx.x, tid = threadIdx.x;
  if (bid < 256){            // E_proj_a64: row bid>>2, col chunk bid&3 (1024 cols)
    const int erow = bid >> 2, cchunk = bid & 3;
    for (int i = tid; i < ZD; i += NT) sz[i] = (double)p.E[erow * ZD + i];
    __syncthreads();
    for (int ci = 0; ci < 4; ++ci){
      const int c = cchunk * 1024 + ci * 256 + tid;
      const float* wr = p.Wih_a + (size_t)c * 768 + 512;
      double a = 0.0;
      for (int j = 0; j < 256; ++j) a = fma((double)wr[j], sz[j], a);
      p.E_proj_a64[(size_t)erow * G4 + c] = a;
    }
  } else if (bid < 512){     // E_proj_t (f32)
    const int erow = (bid - 256) >> 2, cchunk = (bid - 256) & 3;
    for (int i = tid; i < ZD; i += NT) sz[i] = (double)p.E[erow * ZD + i];
    __syncthreads();
    for (int ci = 0; ci < 4; ++ci){
      const int c = cchunk * 1024 + ci * 256 + tid;
      const float* wr = p.Wih_t + (size_t)c * 769 + 512;
      float a = 0.f;
      for (int j = 0; j < 256; ++j) a = fmaf(wr[j], (float)sz[j], a);
      p.E_proj_t[(size_t)erow * G4 + c] = a;
    }
  } else {                   // colt
    const int c = (bid - 512) * 256 + tid;
    p.colt[c] = p.Wih_t[(size_t)c * 769 + 768];
  }
}

// ---------------- tiled f64 GEMM subtile: 64 rows x 32 cols, C += A[.][K] * B[col][K] ----------------
// A: f64 [rows x lda], B: f32 rows (stride ldb), K multiple of 64. acc added to out (+addin).
template <int K>
__device__ void gemm64_subtile(char* smem, const double* __restrict__ A, int lda,
                               const float* __restrict__ B, int ldb,
                               int rowb, int colb, const double* __restrict__ addin,
                               double* __restrict__ outp){
  const int tid = threadIdx.x;
  double* Ash = (double*)smem;                 // [64][66]
  double* Bsh = (double*)(smem + 33792);       // [64][36]
  const int tr = tid & 31, tc = tid >> 5;      // rows 2tr..+1, cols 4tc..+3
  const int arr = tid >> 2, akq = tid & 3;     // A staging: row arr, 16 k at akq*16
  const int brr = tid >> 3, bkq = tid & 7;     // B staging: col brr, 8 k at bkq*8
  double a00=0,a01=0,a02=0,a03=0,a10=0,a11=0,a12=0,a13=0;
  for (int kb = 0; kb < K; kb += 64){
    __syncthreads();
    {
      const double* asrc = A + (size_t)(rowb + arr) * lda + kb + akq * 16;
      #pragma unroll
      for (int kk = 0; kk < 16; ++kk) Ash[(akq * 16 + kk) * 66 + arr] = asrc[kk];
      const float* bsrc = B + (size_t)(colb + brr) * ldb + kb + bkq * 8;
      #pragma unroll
      for (int kk = 0; kk < 8; ++kk) Bsh[(bkq * 8 + kk) * 36 + brr] = (double)bsrc[kk];
    }
    __syncthreads();
    #pragma unroll 4
    for (int k = 0; k < 64; ++k){
      f64x2 a = *(const f64x2*)(Ash + k * 66 + 2 * tr);
      const double* bp = Bsh + k * 36 + 4 * tc;
      f64x2 b01 = *(const f64x2*)(bp);
      f64x2 b23 = *(const f64x2*)(bp + 2);
      a00 = fma(a[0], b01[0], a00); a01 = fma(a[0], b01[1], a01);
      a02 = fma(a[0], b23[0], a02); a03 = fma(a[0], b23[1], a03);
      a10 = fma(a[1], b01[0], a10); a11 = fma(a[1], b01[1], a11);
      a12 = fma(a[1], b23[0], a12); a13 = fma(a[1], b23[1], a13);
    }
  }
  const int r0 = rowb + 2 * tr, c0 = colb + 4 * tc;
  double* o0 = outp + (size_t)r0 * G4 + c0;
  double* o1 = o0 + G4;
  const double* i0 = addin + (size_t)r0 * G4 + c0;
  const double* i1 = i0 + G4;
  o0[0] = a00 + i0[0]; o0[1] = a01 + i0[1]; o0[2] = a02 + i0[2]; o0[3] = a03 + i0[3];
  o1[0] = a10 + i1[0]; o1[1] = a11 + i1[1]; o1[2] = a12 + i1[2]; o1[3] = a13 + i1[3];
}

// same for f64 with bias-vector epilogue (pre kernels)
template <int K>
__device__ void gemm64_subtile_bias(char* smem, const double* __restrict__ A, int lda,
                                    const float* __restrict__ B, int ldb,
                                    int rowb, int colb,
                                    const float* bih, const float* bhh,
                                    double* __restrict__ outp){
  const int tid = threadIdx.x;
  double* Ash = (double*)smem;
  double* Bsh = (double*)(smem + 33792);
  const int tr = tid & 31, tc = tid >> 5;
  const int arr = tid >> 2, akq = tid & 3;
  const int brr = tid >> 3, bkq = tid & 7;
  double a00=0,a01=0,a02=0,a03=0,a10=0,a11=0,a12=0,a13=0;
  for (int kb = 0; kb < K; kb += 64){
    __syncthreads();
    {
      const double* asrc = A + (size_t)(rowb + arr) * lda + kb + akq * 16;
      #pragma unroll
      for (int kk = 0; kk < 16; ++kk) Ash[(akq * 16 + kk) * 66 + arr] = asrc[kk];
      const float* bsrc = B + (size_t)(colb + brr) * ldb + kb + bkq * 8;
      #pragma unroll
      for (int kk = 0; kk < 8; ++kk) Bsh[(bkq * 8 + kk) * 36 + brr] = (double)bsrc[kk];
    }
    __syncthreads();
    #pragma unroll 4
    for (int k = 0; k < 64; ++k){
      f64x2 a = *(const f64x2*)(Ash + k * 66 + 2 * tr);
      const double* bp = Bsh + k * 36 + 4 * tc;
      f64x2 b01 = *(const f64x2*)(bp);
      f64x2 b23 = *(const f64x2*)(bp + 2);
      a00 = fma(a[0], b01[0], a00); a01 = fma(a[0], b01[1], a01);
      a02 = fma(a[0], b23[0], a02); a03 = fma(a[0], b23[1], a03);
      a10 = fma(a[1], b01[0], a10); a11 = fma(a[1], b01[1], a11);
      a12 = fma(a[1], b23[0], a12); a13 = fma(a[1], b23[1], a13);
    }
  }
  const int r0 = rowb + 2 * tr, c0 = colb + 4 * tc;
  double b0 = (double)bih[c0+0] + (double)bhh[c0+0];
  double b1 = (double)bih[c0+1] + (double)bhh[c0+1];
  double b2 = (double)bih[c0+2] + (double)bhh[c0+2];
  double b3 = (double)bih[c0+3] + (double)bhh[c0+3];
  double* o0 = outp + (size_t)r0 * G4 + c0;
  double* o1 = o0 + G4;
  o0[0] = a00 + b0; o0[1] = a01 + b1; o0[2] = a02 + b2; o0[3] = a03 + b3;
  o1[0] = a10 + b0; o1[1] = a11 + b1; o1[2] = a12 + b2; o1[3] = a13 + b3;
}

// ---------------- tiled f32 GEMM subtile: 64 rows x 32 cols ----------------
template <int K, bool BIAS>
__device__ void gemm32_subtile(char* smem, const float* __restrict__ A, int lda,
                               const float* __restrict__ B, int ldb,
                               int rowb, int colb,
                               const float* __restrict__ addin,      // if !BIAS: [row][G4]
                               const float* bih, const float* bhh,   // if BIAS
                               float* __restrict__ outp){
  const int tid = threadIdx.x;
  float* Ash = (float*)smem;                   // [128][66]
  float* Bsh = (float*)(smem + 33792);         // [128][36]
  const int tr = tid & 31, tc = tid >> 5;
  const int arr = tid >> 2, akq = tid & 3;     // A: row arr, 32 k at akq*32
  const int brr = tid >> 3, bkq = tid & 7;     // B: col brr, 16 k at bkq*16
  float a00=0,a01=0,a02=0,a03=0,a10=0,a11=0,a12=0,a13=0;
  for (int kb = 0; kb < K; kb += 128){
    __syncthreads();
    {
      const float* asrc = A + (size_t)(rowb + arr) * lda + kb + akq * 32;
      #pragma unroll
      for (int kk = 0; kk < 32; ++kk) Ash[(akq * 32 + kk) * 66 + arr] = asrc[kk];
      const float* bsrc = B + (size_t)(colb + brr) * ldb + kb + bkq * 16;
      #pragma unroll
      for (int kk = 0; kk < 16; ++kk) Bsh[(bkq * 16 + kk) * 36 + brr] = bsrc[kk];
    }
    __syncthreads();
    #pragma unroll 4
    for (int k = 0; k < 128; ++k){
      f32x2 a = *(const f32x2*)(Ash + k * 66 + 2 * tr);
      f32x4 b = *(const f32x4*)(Bsh + k * 36 + 4 * tc);
      a00 = fmaf(a[0], b[0], a00); a01 = fmaf(a[0], b[1], a01);
      a02 = fmaf(a[0], b[2], a02); a03 = fmaf(a[0], b[3], a03);
      a10 = fmaf(a[1], b[0], a10); a11 = fmaf(a[1], b[1], a11);
      a12 = fmaf(a[1], b[2], a12); a13 = fmaf(a[1], b[3], a13);
    }
  }
  const int r0 = rowb + 2 * tr, c0 = colb + 4 * tc;
  float* o0 = outp + (size_t)r0 * G4 + c0;
  float* o1 = o0 + G4;
  if (BIAS){
    float b0 = bih[c0+0] + bhh[c0+0], b1 = bih[c0+1] + bhh[c0+1];
    float b2 = bih[c0+2] + bhh[c0+2], b3 = bih[c0+3] + bhh[c0+3];
    o0[0] = a00 + b0; o0[1] = a01 + b1; o0[2] = a02 + b2; o0[3] = a03 + b3;
    o1[0] = a10 + b0; o1[1] = a11 + b1; o1[2] = a12 + b2; o1[3] = a13 + b3;
  } else {
    const float* i0 = addin + (size_t)r0 * G4 + c0;
    const float* i1 = i0 + G4;
    o0[0] = a00 + i0[0]; o0[1] = a01 + i0[1]; o0[2] = a02 + i0[2]; o0[3] = a03 + i0[3];
    o1[0] = a10 + i1[0]; o1[1] = a11 + i1[1]; o1[2] = a12 + i1[2]; o1[3] = a13 + i1[3];
  }
}

// ---------------- ts head, j-split (relu-safe): 512 jobs of 8 j-rows ----------------
__device__ void tshead_j(const P& p, int bid, int hbuf){
  const int tid = threadIdx.x;
  const int tm = bid >> 6, tjq = bid & 63;
  const int rowb = tm * 32;
  const int rt = tid >> 3, j8 = tid & 7;
  const int j = tjq * 8 + j8;
  const float* __restrict__ hr = p.h_t + (size_t)hbuf * BB * CF + (size_t)(rowb + rt) * CF;
  const float* __restrict__ wr = p.W_ts1 + (size_t)j * CF;
  float a0=0,a1=0,a2=0,a3=0;
  for (int k = 0; k < CF; k += 16){
    f32x4 h0 = *(const f32x4*)(hr + k),     h1 = *(const f32x4*)(hr + k + 4);
    f32x4 h2 = *(const f32x4*)(hr + k + 8), h3 = *(const f32x4*)(hr + k + 12);
    f32x4 w0 = *(const f32x4*)(wr + k),     w1 = *(const f32x4*)(wr + k + 4);
    f32x4 w2 = *(const f32x4*)(wr + k + 8), w3 = *(const f32x4*)(wr + k + 12);
    a0 = fmaf(h0[0],w0[0], fmaf(h0[1],w0[1], fmaf(h0[2],w0[2], fmaf(h0[3],w0[3], a0))));
    a1 = fmaf(h1[0],w1[0], fmaf(h1[1],w1[1], fmaf(h1[2],w1[2], fmaf(h1[3],w1[3], a1))));
    a2 = fmaf(h2[0],w2[0], fmaf(h2[1],w2[1], fmaf(h2[2],w2[2], fmaf(h2[3],w2[3], a2))));
    a3 = fmaf(h3[0],w3[0], fmaf(h3[1],w3[1], fmaf(h3[2],w3[2], fmaf(h3[3],w3[3], a3))));
  }
  float v = ((a0 + a1) + (a2 + a3)) + p.b_ts1[j];
  v = (v > 0.f ? v : 0.f) * p.W_ts2[j];
  v += __shfl_xor(v, 1, 64);
  v += __shfl_xor(v, 2, 64);
  v += __shfl_xor(v, 4, 64);
  if (j8 == 0) atomicAdd(p.ts_accum + rowb + rt, v);
}

// ---------------- pre kernels (tiled). grid 512: ct = bid&127, rowtile = bid>>7 ----------------
__global__ void __launch_bounds__(NT) k_preA(P p){
  __shared__ __align__(16) char smem[52224];
  const int ct = blockIdx.x & 127, rt4 = blockIdx.x >> 7;
  gemm64_subtile_bias<TD>(smem, p.t_rec64, TD, p.Wih_a, 768,
                          rt4 * 64, ct * 32, p.bih_a, p.bhh_a, p.pre_a64);
}
__global__ void __launch_bounds__(NT) k_preT(P p){
  __shared__ __align__(16) char smem[52224];
  const int ct = blockIdx.x & 127, rt4 = blockIdx.x >> 7;
  gemm32_subtile<TD, true>(smem, p.t_rec32, TD, p.Wih_t, 769,
                           rt4 * 64, ct * 32, nullptr, p.bih_t, p.bhh_t, p.pre_t);
}

// ---------------- step A: homogeneous blocks. grid 512 ----------------
__global__ void __launch_bounds__(NT) k_stepA(P p, int s){
  __shared__ __align__(16) char smem[52224];
  const int bid = blockIdx.x;
  if (s > 0) tshead_j(p, bid, s & 1);           // ts head for step s-1 (no LDS)
  const int ct = bid & 127, rt4 = bid >> 7;     // col tile -> XCD-stable (bid&7 == ct&7)
  const int rowb = rt4 * 64, colb = ct * 32;
  const int rd = s & 1;
  gemm64_subtile<CF>(smem, p.h_a64 + (size_t)rd * BB * CF, CF, p.Whh_a, CF,
                     rowb, colb, p.pre_a64, p.gacc_a);
  __syncthreads();
  gemm32_subtile<CF, false>(smem, p.h_t + (size_t)rd * BB * CF, CF, p.Whh_t, CF,
                            rowb, colb, p.pre_t, nullptr, nullptr, p.gacc_t);
}

// ---------------- step B: LSTM-a pointwise (f64) + logits/argmax/softmax (f64) + LSTM-t (f32) ----------------
__global__ void __launch_bounds__(NT) k_stepB(P p, int s){
  __shared__ double shd[1092];
  const int b = blockIdx.x, tid = threadIdx.x;
  const int cur = (s + 1) & 1;   // h_a/h_t write buffer
  int idxp = p.idxb[b];
  idxp = idxp < 0 ? 0 : (idxp > 63 ? 63 : idxp);
  {
    const double* ga = p.gacc_a + (size_t)b * G4;       // includes pre_a (biases folded)
    const double* ea = p.E_proj_a64 + (size_t)idxp * G4;
    const int c0 = tid * 4;
    #pragma unroll
    for (int jj = 0; jj < 4; ++jj){
      const int c = c0 + jj;
      double gi = ga[0*CF + c] + ea[0*CF + c];
      double gf = ga[1*CF + c] + ea[1*CF + c];
      double gg = ga[2*CF + c] + ea[2*CF + c];
      double go = ga[3*CF + c] + ea[3*CF + c];
      double cv = p.c_a64[(size_t)b * CF + c];
      double cn = sigd(gf) * cv + sigd(gi) * tanh(gg);
      double hn = sigd(go) * tanh(cn);
      p.c_a64[(size_t)b * CF + c] = cn;
      p.h_a64[(size_t)cur * BB * CF + (size_t)b * CF + c] = hn;
      shd[c] = hn;
    }
  }
  if (tid == 0) shd[1088] = (s == 0) ? 0.0 : ((double)p.ts_accum[b] + (double)p.b_ts2[0]);
  __syncthreads();
  {
    const int w = tid >> 6, l = tid & 63, l15 = l & 15, quad = l >> 4;
    const int a = w * 16 + l15;
    const float* wr = p.W_act + (size_t)a * CF + quad * 256;
    const double* hp = shd + quad * 256;
    double acc = 0.0;
    for (int kk = 0; kk < 256; kk += 4){
      acc = fma((double)wr[kk+0], hp[kk+0], acc);
      acc = fma((double)wr[kk+1], hp[kk+1], acc);
      acc = fma((double)wr[kk+2], hp[kk+2], acc);
      acc = fma((double)wr[kk+3], hp[kk+3], acc);
    }
    acc += __shfl_xor(acc, 16, 64);
    acc += __shfl_xor(acc, 32, 64);
    if (quad == 0) shd[1024 + a] = acc;
  }
  __syncthreads();
  if (tid < 64){
    double acc = shd[1024 + tid] + (double)p.b_act[tid];
    double m = acc;
    #pragma unroll
    for (int off = 32; off; off >>= 1) m = fmax(m, __shfl_xor(m, off, 64));
    unsigned long long ball = __ballot(acc == m);
    int idxv = __ffsll(ball) - 1;               // first max == np.argmax
    idxv = idxv < 0 ? 0 : (idxv > 63 ? 63 : idxv);
    double e = exp(acc - m);
    double ssum = e;
    #pragma unroll
    for (int off = 32; off; off >>= 1) ssum += __shfl_xor(ssum, off, 64);
    p.out[(size_t)b * (NSTEP * NA) + s * NA + tid] = (float)(e / ssum);
    if (tid == 0){
      p.idxb[b] = idxv;
      shd[1089] = (double)idxv;
      if (s > 0) p.out[TS_OFF + b * NSTEP + (s - 1)] = (float)shd[1088];
    }
  }
  __syncthreads();
  const float ts_val = (float)shd[1088];
  const int idxv = (int)shd[1089];
  const int c0 = tid * 4;
  const float* gb = p.gacc_t   + (size_t)b * G4;   // includes pre_t (biases folded)
  const float* eb = p.E_proj_t + (size_t)idxv * G4;
  f32x4 gi = *(const f32x4*)(gb + 0*CF + c0) + *(const f32x4*)(eb + 0*CF + c0) + ts_val * *(const f32x4*)(p.colt + 0*CF + c0);
  f32x4 gf = *(const f32x4*)(gb + 1*CF + c0) + *(const f32x4*)(eb + 1*CF + c0) + ts_val * *(const f32x4*)(p.colt + 1*CF + c0);
  f32x4 gg = *(const f32x4*)(gb + 2*CF + c0) + *(const f32x4*)(eb + 2*CF + c0) + ts_val * *(const f32x4*)(p.colt + 2*CF + c0);
  f32x4 go = *(const f32x4*)(gb + 3*CF + c0) + *(const f32x4*)(eb + 3*CF + c0) + ts_val * *(const f32x4*)(p.colt + 3*CF + c0);
  f32x4 cv = *(f32x4*)(p.c_t + (size_t)b * CF + c0);
  f32x4 cn, hn;
  #pragma unroll
  for (int jj = 0; jj < 4; ++jj){
    float cj = sigf(gf[jj]) * cv[jj] + sigf(gi[jj]) * tanhf_(gg[jj]);
    float hj = sigf(go[jj]) * tanhf_(cj);
    cn[jj] = cj; hn[jj] = hj;
  }
  *(f32x4*)(p.c_t + (size_t)b * CF + c0) = cn;
  *(f32x4*)(p.h_t + (size_t)cur * BB * CF + (size_t)b * CF + c0) = hn;
  __syncthreads();
  if (tid == 0) p.ts_accum[b] = 0.f;   // ready for next step's tshead accumulation
}

// final ts head for step 63 (h_t buffer 0) + write
__global__ void __launch_bounds__(NT) k_tsfin(P p){
  tshead_j(p, blockIdx.x, 0);
}
__global__ void __launch_bounds__(NT) k_tswrite(P p){
  p.out[TS_OFF + threadIdx.x * NSTEP + 63] = p.ts_accum[threadIdx.x] + p.b_ts2[0];
}

extern "C" void kernel_launch(void* const* d_in, const int* in_sizes, int n_in,
                              void* d_out, int out_size, void* d_ws, size_t ws_size,
                              hipStream_t stream){
  (void)in_sizes; (void)n_in; (void)out_size; (void)ws_size;
  P p;
  p.z     = (const float*)d_in[0];  p.W_z2t = (const float*)d_in[1];  p.b_z2t = (const float*)d_in[2];
  p.E     = (const float*)d_in[3];  p.Wih_a = (const float*)d_in[4];  p.Whh_a = (const float*)d_in[5];
  p.bih_a = (const float*)d_in[6];  p.bhh_a = (const float*)d_in[7];  p.Wih_t = (const float*)d_in[8];
  p.Whh_t = (const float*)d_in[9];  p.bih_t = (const float*)d_in[10]; p.bhh_t = (const float*)d_in[11];
  p.W_act = (const float*)d_in[12]; p.b_act = (const float*)d_in[13]; p.W_ts1 = (const float*)d_in[14];
  p.b_ts1 = (const float*)d_in[15]; p.W_ts2 = (const float*)d_in[16]; p.b_ts2 = (const float*)d_in[17];
  p.out = (float*)d_out;
  char* w = (char*)d_ws;
  size_t off = 0;
  auto alloc = [&](size_t bytes) -> void* { void* r = w + off; off += (bytes + 255) & ~(size_t)255; return r; };
  p.t_rec64    = (double*)alloc((size_t)BB * TD * 8);
  p.pre_a64    = (double*)alloc((size_t)BB * G4 * 8);
  p.E_proj_a64 = (double*)alloc((size_t)NA * G4 * 8);
  p.h_a64      = (double*)alloc((size_t)2 * BB * CF * 8);
  p.c_a64      = (double*)alloc((size_t)BB * CF * 8);
  p.gacc_a     = (double*)alloc((size_t)BB * G4 * 8);
  p.t_rec32    = (float*)alloc((size_t)BB * TD * 4);
  p.pre_t      = (float*)alloc((size_t)BB * G4 * 4);
  p.E_proj_t   = (float*)alloc((size_t)NA * G4 * 4);
  p.colt       = (float*)alloc((size_t)G4 * 4);
  p.h_t        = (float*)alloc((size_t)2 * BB * CF * 4);
  p.c_t        = (float*)alloc((size_t)BB * CF * 4);
  p.gacc_t     = (float*)alloc((size_t)BB * G4 * 4);
  p.ts_accum   = (float*)alloc((size_t)BB * 4);
  p.idxb       = (int*)  alloc((size_t)BB * 4);

  k_setup<<<dim3(256), dim3(NT), 0, stream>>>(p);
  k_eproj<<<dim3(528), dim3(NT), 0, stream>>>(p);
  k_preA <<<dim3(512), dim3(NT), 0, stream>>>(p);
  k_preT <<<dim3(512), dim3(NT), 0, stream>>>(p);
  for (int s = 0; s < NSTEP; ++s){
    k_stepA<<<dim3(512), dim3(NT), 0, stream>>>(p, s);
    k_stepB<<<dim3(256), dim3(NT), 0, stream>>>(p, s);
  }
  k_tsfin  <<<dim3(512), dim3(NT), 0, stream>>>(p);
  k_tswrite<<<dim3(1),   dim3(NT), 0, stream>>>(p);
}